// Round 5
// baseline (5218.132 us; speedup 1.0000x reference)
//
#include <hip/hip_runtime.h>
#include <stdint.h>

// Problem constants (reference: EMB=256, HID=1024, N_TRACKS=4096, SEQ=9, n_predict=12)
#define NTRK 4096
#define HIDN 1024
#define EMBN 256
#define KTOT 1280   // EMB + HID
#define NOUT 19     // 8 enc + 11 dec steps

typedef __attribute__((ext_vector_type(8))) short short8;
typedef __attribute__((ext_vector_type(4))) float f32x4;

typedef __attribute__((address_space(1))) const void GV;
typedef __attribute__((address_space(3))) void LV;

__device__ __forceinline__ uint16_t f2bf(float f) {
  uint32_t u = __float_as_uint(f);
  u += 0x7fffu + ((u >> 16) & 1u);   // round-to-nearest-even
  return (uint16_t)(u >> 16);
}
__device__ __forceinline__ float bf2f(uint16_t v) {
  return __uint_as_float(((uint32_t)v) << 16);
}
// precise versions (setup kernels only)
__device__ __forceinline__ float sigm(float x) { return 1.0f / (1.0f + expf(-x)); }
// fast versions (hot epilogue): v_exp + v_rcp, ~1e-6 abs error (margin is 5.5x)
__device__ __forceinline__ float sigmf_(float x) {
  return __builtin_amdgcn_rcpf(1.0f + __expf(-x));
}
__device__ __forceinline__ float tanhf_(float x) {
  // tanh(x) = 2*sigm(2x)-1; exp overflow/underflow saturates correctly
  return 2.0f * __builtin_amdgcn_rcpf(1.0f + __expf(-2.0f * x)) - 1.0f;
}

// -------------------------------------------------------------------------
// Weight prep (16-unit gate groups): permuted row j' = q*64 + gate*16 + u16
// maps to original row gate*1024 + (q*16+u16). A 64-wide wave N-tile holds
// the 4 gates (i,f,g,o) of 16 hidden units -> LSTM pointwise is lane-local.
// -------------------------------------------------------------------------
__global__ __launch_bounds__(256) void prep_weights(
    const float* __restrict__ encWih, const float* __restrict__ encWhh,
    const float* __restrict__ encB,
    const float* __restrict__ decWih, const float* __restrict__ decWhh,
    const float* __restrict__ decB,
    uint16_t* __restrict__ WihpE, uint16_t* __restrict__ WhhpE,
    uint16_t* __restrict__ WihpD, uint16_t* __restrict__ WhhpD,
    float* __restrict__ biasE, float* __restrict__ biasD, float* __restrict__ biasDT)
{
  const int jp = blockIdx.x;                 // permuted row 0..4095
  const int q = jp >> 6, r = jp & 63;
  const int gate = r >> 4, l16 = r & 15;
  const int u = q * 16 + l16;
  const int orig = gate * 1024 + u;
  const int t = threadIdx.x;                 // 0..255

  WihpE[(size_t)jp * 256 + t] = f2bf(encWih[(size_t)orig * 256 + t]);
  WihpD[(size_t)jp * 256 + t] = f2bf(decWih[(size_t)orig * 256 + t]);
#pragma unroll
  for (int c = 0; c < 4; c++) {
    WhhpE[(size_t)jp * 1024 + c * 256 + t] = f2bf(encWhh[(size_t)orig * 1024 + c * 256 + t]);
    WhhpD[(size_t)jp * 1024 + c * 256 + t] = f2bf(decWhh[(size_t)orig * 1024 + c * 256 + t]);
  }
  if (t == 0) {
    biasE[jp]  = encB[orig];
    biasD[jp]  = decB[orig];
    biasDT[jp] = decB[orig] + decWih[(size_t)orig * 256 + 255]; // dec tag one-hot col 255
  }
}

// Enc-tag cell with h=c=0: gates identical for all tracks -> closed form.
__global__ void init_h0(const float* __restrict__ encWih, const float* __restrict__ encB,
                        float* __restrict__ h0, float* __restrict__ c0)
{
  const int u = blockIdx.x * 256 + threadIdx.x;   // 0..1023
  if (u >= 1024) return;
  const float gi = encWih[(size_t)(u) * 256 + 254]        + encB[u];
  const float gg = encWih[(size_t)(2048 + u) * 256 + 254] + encB[2048 + u];
  const float go = encWih[(size_t)(3072 + u) * 256 + 254] + encB[3072 + u];
  const float c = sigm(gi) * tanhf(gg);   // sigm(gf)*0 + ...
  c0[u] = c;
  h0[u] = sigm(go) * tanhf(c);
}

__global__ void fill_state(const float* __restrict__ h0, const float* __restrict__ c0,
                           uint16_t* __restrict__ H, float* __restrict__ Cst)
{
  const size_t i = (size_t)blockIdx.x * 256 + threadIdx.x;  // 4096*1024 total
  const int u = (int)(i & 1023);
  H[i] = f2bf(h0[u]);
  Cst[i] = c0[u];
}

__global__ void zero_cnt(int* __restrict__ cnt, int n)
{
  const int i = blockIdx.x * 256 + threadIdx.x;
  if (i < n) cnt[i] = 0;
}

// embed fallback for one encoder step (if workspace can't hold Xall)
__global__ __launch_bounds__(256) void embed_k(
    const float* __restrict__ o1, const float* __restrict__ o2,
    const float* __restrict__ ew, const float* __restrict__ eb,
    uint16_t* __restrict__ X)
{
  const int trk = blockIdx.x;
  const int j = threadIdx.x;
  const float vx = (o2[trk * 2]     - o1[trk * 2])     * 4.0f;
  const float vy = (o2[trk * 2 + 1] - o1[trk * 2 + 1]) * 4.0f;
  float e = 0.f;
  if (j < 254) e = fmaxf(vx * ew[j * 2] + vy * ew[j * 2 + 1] + eb[j], 0.f);
  X[(size_t)trk * 256 + j] = f2bf(e);
}

// All 8 encoder embeds in one dispatch (inputs known upfront).
__global__ __launch_bounds__(256) void embed8(
    const float* __restrict__ observed, const float* __restrict__ ew,
    const float* __restrict__ eb, uint16_t* __restrict__ Xall)
{
  const int t = blockIdx.y;          // 0..7
  const int trk = blockIdx.x;
  const int j = threadIdx.x;
  const float* o1 = observed + ((size_t)t * 4096 + trk) * 2;
  const float* o2 = o1 + 4096 * 2;
  const float vx = (o2[0] - o1[0]) * 4.0f;
  const float vy = (o2[1] - o1[1]) * 4.0f;
  float e = 0.f;
  if (j < 254) e = fmaxf(vx * ew[j * 2] + vy * ew[j * 2 + 1] + eb[j], 0.f);
  Xall[((size_t)t * 4096 + trk) * 256 + j] = f2bf(e);
}

// -------------------------------------------------------------------------
// Per-wave h2n for ONE track: raw = h @ h2n_w.T + h2n_b, butterfly-reduced so
// ALL lanes hold the sums; lane0 writes outrel/outpos; all lanes embed the
// next step's X (4 cols each) when do_embed.
// -------------------------------------------------------------------------
__device__ __forceinline__ void h2n_one(
    int track, int lane,
    const uint16_t* __restrict__ H, const float* __restrict__ w5,
    const float* __restrict__ b5,
    const float* __restrict__ obs1, const float* __restrict__ obs2,
    float* __restrict__ outrel, float* __restrict__ outpos,
    const float* __restrict__ pprev, const float* __restrict__ ew,
    const float* __restrict__ eb, uint16_t* __restrict__ Xnext, int do_embed)
{
  const uint16_t* hrow = H + (size_t)track * 1024 + lane * 16;
  const short8 v0 = *(const short8*)(hrow);
  const short8 v1 = *(const short8*)(hrow + 8);
  float hv[16];
#pragma unroll
  for (int j = 0; j < 8; j++) {
    hv[j]     = bf2f((uint16_t)v0[j]);
    hv[8 + j] = bf2f((uint16_t)v1[j]);
  }
  float p[5];
#pragma unroll
  for (int o = 0; o < 5; o++) {
    const float* wr = w5 + (size_t)o * 1024 + lane * 16;
    float s = 0.f;
#pragma unroll
    for (int j = 0; j < 16; j++) s += hv[j] * wr[j];
    p[o] = s;
  }
#pragma unroll
  for (int o = 0; o < 5; o++) {
    float v = p[o];
    v += __shfl_xor(v, 32); v += __shfl_xor(v, 16); v += __shfl_xor(v, 8);
    v += __shfl_xor(v, 4);  v += __shfl_xor(v, 2);  v += __shfl_xor(v, 1);
    p[o] = v;
  }
  const float o1x = obs1[track * 2];
  const float o2x = obs2[track * 2];
  const float o2y = obs2[track * 2 + 1];
  const bool msk = !((o1x != o1x) || (o2x != o2x));
  float n0 = p[0] + b5[0];
  float n1 = p[1] + b5[1];
  float n2 = 0.01f + 0.2f * sigmf_(p[2] + b5[2]);
  float n3 = 0.01f + 0.2f * sigmf_(p[3] + b5[3]);
  float n4 = 0.7f  * sigmf_(p[4] + b5[4]);
  if (!msk) {
    const float qn = __uint_as_float(0x7fc00000u);
    n0 = n1 = n2 = n3 = n4 = qn;
  }
  const float posx = o2x + n0;
  const float posy = o2y + n1;
  if (lane == 0) {
    float* rr = outrel + (size_t)track * 5;
    rr[0] = n0; rr[1] = n1; rr[2] = n2; rr[3] = n3; rr[4] = n4;
    outpos[track * 2]     = posx;
    outpos[track * 2 + 1] = posy;
  }
  if (do_embed) {
    const float vx = (posx - pprev[track * 2])     * 4.0f;
    const float vy = (posy - pprev[track * 2 + 1]) * 4.0f;
    uint16_t* xr = Xnext + (size_t)track * 256;
#pragma unroll
    for (int ii = 0; ii < 4; ii++) {
      const int j = ii * 64 + lane;
      float e = 0.f;
      if (j < 254) e = fmaxf(vx * ew[j * 2] + vy * ew[j * 2 + 1] + eb[j], 0.f);
      xr[j] = f2bf(e);   // NaN inputs -> fmax gives 0; row is masked anyway
    }
  }
}

// -------------------------------------------------------------------------
// Fused LSTM-cell GEMM (R2 control geometry): G = [X|H] @ [Wih|Whh]^T + bias,
// gated update in epilogue. 128x128 block, BK=64, 4 waves (2x2 of 64x64),
// mfma_f32_16x16x32_bf16, global_load_lds width 16, XOR chunk swizzle
// (conflicts measured 0), 4 blocks/CU (VGPR capped at 128 by launch_bounds).
//
// R5 addition: fused h2n tail. Each bn-block bumps cnt[bm-slab] after a
// device-scope release fence; the 32nd (winner) runs h2n (+ next-step embed)
// for its 128 tracks — removes the separate h2n dispatch per step.
// flags: bit0 = NaN-mask, bit1 = h2n tail, bit2 = embed next X.
// -------------------------------------------------------------------------
__global__ __launch_bounds__(256, 4) void gemm_lstm(
    const uint16_t* __restrict__ X,   const uint16_t* __restrict__ Hin,
    const uint16_t* __restrict__ Wih, const uint16_t* __restrict__ Whh,
    const float* __restrict__ bias,   float* __restrict__ Cst,
    uint16_t* __restrict__ Hout,
    const float* __restrict__ obs1,   const float* __restrict__ obs2,
    int k0, int flags,
    const float* __restrict__ w5, const float* __restrict__ b5,
    float* __restrict__ outrel, float* __restrict__ outpos,
    const float* __restrict__ pprev, const float* __restrict__ ew,
    const float* __restrict__ eb, uint16_t* __restrict__ Xnext,
    int* __restrict__ cnt)
{
  __shared__ uint16_t As[128 * 64];
  __shared__ uint16_t Bs[128 * 64];
  __shared__ uint8_t  smask[128];
  __shared__ int      win;

  const int tid  = threadIdx.x;
  const int wave = tid >> 6;
  const int lane = tid & 63;
  const int bm = blockIdx.y * 128;   // track rows
  const int bn = blockIdx.x * 128;   // permuted gate cols

  if (tid < 128) {
    bool m = true;
    if (flags & 1) {
      const int row = bm + tid;
      const float a = obs1[row * 2];
      const float b = obs2[row * 2];
      m = !((a != a) || (b != b));
    }
    smask[tid] = m ? 1 : 0;
  }

  const int wrow = wave >> 1;
  const int wcol = wave & 1;
  const int quad = lane >> 4;
  const int l15  = lane & 15;
  const int m7   = l15 & 7;
  const int lr = lane >> 3;                  // row within 8-row staging chunk
  const int lj = ((lane & 7) ^ lr) * 8;      // swizzled global k-offset (elements)

  f32x4 acc[4][4];
#pragma unroll
  for (int i = 0; i < 4; i++)
#pragma unroll
    for (int j = 0; j < 4; j++) acc[i][j] = (f32x4){0.f, 0.f, 0.f, 0.f};

  auto mfma_slab = [&]() {
#pragma unroll
    for (int kk = 0; kk < 64; kk += 32) {
      short8 af[4], bf[4];
      const int jc = (((kk >> 3) + quad) ^ m7) * 8;   // swizzled read chunk
#pragma unroll
      for (int i = 0; i < 4; i++) {
        af[i] = *(const short8*)(As + (wrow * 64 + i * 16 + l15) * 64 + jc);
        bf[i] = *(const short8*)(Bs + (wcol * 64 + i * 16 + l15) * 64 + jc);
      }
#pragma unroll
      for (int i = 0; i < 4; i++)
#pragma unroll
        for (int j = 0; j < 4; j++)
          acc[i][j] = __builtin_amdgcn_mfma_f32_16x16x32_bf16(af[i], bf[j], acc[i][j], 0, 0, 0);
    }
  };

  // ---- phase A: X | Wih segment (row stride 256), skipped for tag step ----
  if (k0 == 0) {
    for (int kt = 0; kt < 256; kt += 64) {
      __syncthreads();
#pragma unroll
      for (int cc = 0; cc < 8; cc++) {
        const bool isA = cc < 4;
        const int trow = ((cc & 3) * 4 + wave) * 8;
        const int grow = (isA ? bm : bn) + trow + lr;
        const uint16_t* gsrc = (isA ? X : Wih) + (size_t)grow * 256 + (kt + lj);
        uint16_t* lbase = (isA ? As : Bs) + trow * 64;
        __builtin_amdgcn_global_load_lds((GV*)gsrc, (LV*)lbase, 16, 0, 0);
      }
      __syncthreads();
      mfma_slab();
    }
  }

  // ---- phase B: Hin | Whh segment (row stride 1024) ----
  for (int kt = 0; kt < 1024; kt += 64) {
    __syncthreads();
#pragma unroll
    for (int cc = 0; cc < 8; cc++) {
      const bool isA = cc < 4;
      const int trow = ((cc & 3) * 4 + wave) * 8;
      const int grow = (isA ? bm : bn) + trow + lr;
      const uint16_t* gsrc = (isA ? Hin : Whh) + (size_t)grow * 1024 + (kt + lj);
      uint16_t* lbase = (isA ? As : Bs) + trow * 64;
      __builtin_amdgcn_global_load_lds((GV*)gsrc, (LV*)lbase, 16, 0, 0);
    }
    __syncthreads();
    mfma_slab();
  }

  // Epilogue: N-tiles 0..3 = gates i,f,g,o of units u = ((bn>>6)+wcol)*16+l15.
  // C/D layout: col = lane&15, row = quad*4 + reg  [m89-verified]
  const int u  = ((bn >> 6) + wcol) * 16 + l15;
  const int jb = bn + wcol * 64 + l15;
  const float b_i = bias[jb];
  const float b_f = bias[jb + 16];
  const float b_g = bias[jb + 32];
  const float b_o = bias[jb + 48];

#pragma unroll
  for (int mi = 0; mi < 4; mi++) {
#pragma unroll
    for (int r = 0; r < 4; r++) {
      const int row = bm + wrow * 64 + mi * 16 + quad * 4 + r;
      const size_t idx = (size_t)row * 1024 + u;
      uint16_t hv;
      if (smask[row - bm]) {
        const float gi = acc[mi][0][r] + b_i;
        const float gf = acc[mi][1][r] + b_f;
        const float gg = acc[mi][2][r] + b_g;
        const float go = acc[mi][3][r] + b_o;
        const float cn = sigmf_(gf) * Cst[idx] + sigmf_(gi) * tanhf_(gg);
        Cst[idx] = cn;
        hv = f2bf(sigmf_(go) * tanhf_(cn));
      } else {
        hv = Hin[idx];        // state frozen; Hout is a different buffer
      }
      Hout[idx] = hv;
    }
  }

  // ---- fused h2n tail: last bn-block of this bm-slab does the row outputs ----
  if (flags & 2) {
    __threadfence();                          // release Hout stores (device scope)
    if (tid == 0) {
      const int old = atomicAdd(cnt + blockIdx.y, 1);
      win = (old == 31) ? 1 : 0;
    }
    __syncthreads();
    if (win) {
      __threadfence();                        // acquire side
      const int base = bm + wave * 32;
      for (int it = 0; it < 32; it++) {
        h2n_one(base + it, lane, Hout, w5, b5, obs1, obs2,
                outrel, outpos, pprev, ew, eb, Xnext, flags & 4);
      }
    }
  }
}

// -------------------------------------------------------------------------
extern "C" void kernel_launch(void* const* d_in, const int* in_sizes, int n_in,
                              void* d_out, int out_size, void* d_ws, size_t ws_size,
                              hipStream_t stream)
{
  const float* observed = (const float*)d_in[0];
  const float* emb_w    = (const float*)d_in[1];
  const float* emb_b    = (const float*)d_in[2];
  const float* enc_wih  = (const float*)d_in[3];
  const float* enc_whh  = (const float*)d_in[4];
  const float* enc_b    = (const float*)d_in[5];
  const float* dec_wih  = (const float*)d_in[6];
  const float* dec_whh  = (const float*)d_in[7];
  const float* dec_b    = (const float*)d_in[8];
  const float* h2n_w    = (const float*)d_in[9];
  const float* h2n_b    = (const float*)d_in[10];
  // d_in[11] = n_predict (==12, fixed by setup)

  char* ws = (char*)d_ws;
  size_t off = 0;
  auto alloc = [&](size_t bytes) -> void* {
    size_t cur = (off + 255) & ~(size_t)255;
    off = cur + bytes;
    return (void*)(ws + cur);
  };
  uint16_t* WihpE = (uint16_t*)alloc((size_t)4096 * 256 * 2);
  uint16_t* WhhpE = (uint16_t*)alloc((size_t)4096 * 1024 * 2);
  uint16_t* WihpD = (uint16_t*)alloc((size_t)4096 * 256 * 2);
  uint16_t* WhhpD = (uint16_t*)alloc((size_t)4096 * 1024 * 2);
  float*    biasE = (float*)alloc(4096 * 4);
  float*    biasD = (float*)alloc(4096 * 4);
  float*    biasDT= (float*)alloc(4096 * 4);
  float*    h0    = (float*)alloc(1024 * 4);
  float*    c0    = (float*)alloc(1024 * 4);
  uint16_t* HA    = (uint16_t*)alloc((size_t)4096 * 1024 * 2);
  uint16_t* HB    = (uint16_t*)alloc((size_t)4096 * 1024 * 2);
  float*    Cst   = (float*)alloc((size_t)4096 * 1024 * 4);
  uint16_t* XbA   = (uint16_t*)alloc((size_t)4096 * 256 * 2);
  uint16_t* XbB   = (uint16_t*)alloc((size_t)4096 * 256 * 2);
  int*      cnt   = (int*)alloc(20 * 32 * 4);
  // optional batched encoder X (16 MB) — only if workspace allows
  const size_t xall_bytes = (size_t)8 * 4096 * 256 * 2;
  const bool use_xall = (off + 256 + xall_bytes) <= ws_size;
  uint16_t* Xall = use_xall ? (uint16_t*)alloc(xall_bytes) : nullptr;

  float* outrel = (float*)d_out;                     // (19, 4096, 5)
  float* outpos = outrel + (size_t)NOUT * 4096 * 5;  // (19, 4096, 2)

  prep_weights<<<4096, 256, 0, stream>>>(enc_wih, enc_whh, enc_b, dec_wih, dec_whh, dec_b,
                                         WihpE, WhhpE, WihpD, WhhpD, biasE, biasD, biasDT);
  init_h0<<<4, 256, 0, stream>>>(enc_wih, enc_b, h0, c0);
  fill_state<<<16384, 256, 0, stream>>>(h0, c0, HA, Cst);
  zero_cnt<<<3, 256, 0, stream>>>(cnt, 20 * 32);
  if (use_xall) {
    embed8<<<dim3(4096, 8), 256, 0, stream>>>(observed, emb_w, emb_b, Xall);
  }

  uint16_t* Hin = HA;
  uint16_t* Hout = HB;
  const dim3 ggrid(32, 32);

  // ---- encoder: 8 steps over observed pairs ----
  for (int t = 0; t < 8; t++) {
    const float* o1 = observed + (size_t)t * 4096 * 2;
    const float* o2 = observed + (size_t)(t + 1) * 4096 * 2;
    uint16_t* Xt = XbA;
    if (use_xall) {
      Xt = Xall + (size_t)t * 4096 * 256;
    } else {
      embed_k<<<4096, 256, 0, stream>>>(o1, o2, emb_w, emb_b, XbA);
    }
    // flags: mask | h2n | (t==7: embed first decoder X into XbA)
    const int flags = 1 | 2 | ((t == 7) ? 4 : 0);
    gemm_lstm<<<ggrid, 256, 0, stream>>>(
        Xt, Hin, WihpE, WhhpE, biasE, Cst, Hout, o1, o2, 0, flags,
        h2n_w, h2n_b,
        outrel + (size_t)t * 4096 * 5, outpos + (size_t)t * 4096 * 2,
        outpos + (size_t)6 * 4096 * 2, emb_w, emb_b, XbA, cnt + t * 32);
    uint16_t* tmp = Hin; Hin = Hout; Hout = tmp;
  }

  // ---- decoder tag cell (no outputs; x one-hot folded into biasDT) ----
  gemm_lstm<<<ggrid, 256, 0, stream>>>(
      nullptr, Hin, WihpD, WhhpD, biasDT, Cst, Hout, nullptr, nullptr, 256, 0,
      nullptr, nullptr, nullptr, nullptr, nullptr, nullptr, nullptr, nullptr, nullptr);
  { uint16_t* tmp = Hin; Hin = Hout; Hout = tmp; }

  // ---- decoder: 11 steps; X ping-pongs between XbA/XbB via fused embed ----
  for (int s = 0; s < 11; s++) {
    const float* p1 = outpos + (size_t)(6 + s) * 4096 * 2;
    const float* p2 = outpos + (size_t)(7 + s) * 4096 * 2;
    uint16_t* Xcur  = (s & 1) ? XbB : XbA;
    uint16_t* Xnext = (s & 1) ? XbA : XbB;
    const int flags = 1 | 2 | ((s < 10) ? 4 : 0);
    gemm_lstm<<<ggrid, 256, 0, stream>>>(
        Xcur, Hin, WihpD, WhhpD, biasD, Cst, Hout, p1, p2, 0, flags,
        h2n_w, h2n_b,
        outrel + (size_t)(8 + s) * 4096 * 5, outpos + (size_t)(8 + s) * 4096 * 2,
        p2, emb_w, emb_b, Xnext, cnt + (8 + s) * 32);
    uint16_t* tmp = Hin; Hin = Hout; Hout = tmp;
  }
}

// Round 6
// 1476.631 us; speedup vs baseline: 3.5338x; 3.5338x over previous
//
#include <hip/hip_runtime.h>
#include <stdint.h>

// Problem constants (reference: EMB=256, HID=1024, N_TRACKS=4096, SEQ=9, n_predict=12)
#define NTRK 4096
#define HIDN 1024
#define EMBN 256
#define KTOT 1280   // EMB + HID
#define NOUT 19     // 8 enc + 11 dec steps

typedef __attribute__((ext_vector_type(8))) short short8;
typedef __attribute__((ext_vector_type(4))) float f32x4;

typedef __attribute__((address_space(1))) const void GV;
typedef __attribute__((address_space(3))) void LV;

__device__ __forceinline__ uint16_t f2bf(float f) {
  uint32_t u = __float_as_uint(f);
  u += 0x7fffu + ((u >> 16) & 1u);   // round-to-nearest-even
  return (uint16_t)(u >> 16);
}
__device__ __forceinline__ float bf2f(uint16_t v) {
  return __uint_as_float(((uint32_t)v) << 16);
}
// precise (setup only)
__device__ __forceinline__ float sigm(float x) { return 1.0f / (1.0f + expf(-x)); }
// fast (hot paths): v_exp + v_rcp; error ~1e-6, margin is 5.5x
__device__ __forceinline__ float sigmf_(float x) {
  return __builtin_amdgcn_rcpf(1.0f + __expf(-x));
}
__device__ __forceinline__ float tanhf_(float x) {
  return 2.0f * __builtin_amdgcn_rcpf(1.0f + __expf(-2.0f * x)) - 1.0f;
}

// -------------------------------------------------------------------------
// Weight prep (16-unit gate groups): permuted row j' = q*64 + gate*16 + u16
// maps to original row gate*1024 + (q*16+u16). A 64-wide wave N-tile holds
// the 4 gates (i,f,g,o) of 16 hidden units -> LSTM pointwise is lane-local.
// -------------------------------------------------------------------------
__global__ __launch_bounds__(256) void prep_weights(
    const float* __restrict__ encWih, const float* __restrict__ encWhh,
    const float* __restrict__ encB,
    const float* __restrict__ decWih, const float* __restrict__ decWhh,
    const float* __restrict__ decB,
    uint16_t* __restrict__ WihpE, uint16_t* __restrict__ WhhpE,
    uint16_t* __restrict__ WihpD, uint16_t* __restrict__ WhhpD,
    float* __restrict__ biasE, float* __restrict__ biasD, float* __restrict__ biasDT)
{
  const int jp = blockIdx.x;                 // permuted row 0..4095
  const int q = jp >> 6, r = jp & 63;
  const int gate = r >> 4, l16 = r & 15;
  const int u = q * 16 + l16;
  const int orig = gate * 1024 + u;
  const int t = threadIdx.x;                 // 0..255

  WihpE[(size_t)jp * 256 + t] = f2bf(encWih[(size_t)orig * 256 + t]);
  WihpD[(size_t)jp * 256 + t] = f2bf(decWih[(size_t)orig * 256 + t]);
#pragma unroll
  for (int c = 0; c < 4; c++) {
    WhhpE[(size_t)jp * 1024 + c * 256 + t] = f2bf(encWhh[(size_t)orig * 1024 + c * 256 + t]);
    WhhpD[(size_t)jp * 1024 + c * 256 + t] = f2bf(decWhh[(size_t)orig * 1024 + c * 256 + t]);
  }
  if (t == 0) {
    biasE[jp]  = encB[orig];
    biasD[jp]  = decB[orig];
    biasDT[jp] = decB[orig] + decWih[(size_t)orig * 256 + 255]; // dec tag one-hot col 255
  }
}

// Enc-tag cell with h=c=0: gates identical for all tracks -> closed form.
__global__ void init_h0(const float* __restrict__ encWih, const float* __restrict__ encB,
                        float* __restrict__ h0, float* __restrict__ c0)
{
  const int u = blockIdx.x * 256 + threadIdx.x;   // 0..1023
  if (u >= 1024) return;
  const float gi = encWih[(size_t)(u) * 256 + 254]        + encB[u];
  const float gg = encWih[(size_t)(2048 + u) * 256 + 254] + encB[2048 + u];
  const float go = encWih[(size_t)(3072 + u) * 256 + 254] + encB[3072 + u];
  const float c = sigm(gi) * tanhf(gg);   // sigm(gf)*0 + ...
  c0[u] = c;
  h0[u] = sigm(go) * tanhf(c);
}

__global__ void fill_state(const float* __restrict__ h0, const float* __restrict__ c0,
                           uint16_t* __restrict__ H, float* __restrict__ Cst)
{
  const size_t i = (size_t)blockIdx.x * 256 + threadIdx.x;  // 4096*1024 total
  const int u = (int)(i & 1023);
  H[i] = f2bf(h0[u]);
  Cst[i] = c0[u];
}

// embed fallback for one encoder step (if workspace can't hold Xall)
__global__ __launch_bounds__(256) void embed_k(
    const float* __restrict__ o1, const float* __restrict__ o2,
    const float* __restrict__ ew, const float* __restrict__ eb,
    uint16_t* __restrict__ X)
{
  const int trk = blockIdx.x;
  const int j = threadIdx.x;
  const float vx = (o2[trk * 2]     - o1[trk * 2])     * 4.0f;
  const float vy = (o2[trk * 2 + 1] - o1[trk * 2 + 1]) * 4.0f;
  float e = 0.f;
  if (j < 254) e = fmaxf(vx * ew[j * 2] + vy * ew[j * 2 + 1] + eb[j], 0.f);
  X[(size_t)trk * 256 + j] = f2bf(e);
}

// All 8 encoder embeds in one dispatch (inputs known upfront).
__global__ __launch_bounds__(256) void embed8(
    const float* __restrict__ observed, const float* __restrict__ ew,
    const float* __restrict__ eb, uint16_t* __restrict__ Xall)
{
  const int t = blockIdx.y;          // 0..7
  const int trk = blockIdx.x;
  const int j = threadIdx.x;
  const float* o1 = observed + ((size_t)t * 4096 + trk) * 2;
  const float* o2 = o1 + 4096 * 2;
  const float vx = (o2[0] - o1[0]) * 4.0f;
  const float vy = (o2[1] - o1[1]) * 4.0f;
  float e = 0.f;
  if (j < 254) e = fmaxf(vx * ew[j * 2] + vy * ew[j * 2 + 1] + eb[j], 0.f);
  Xall[((size_t)t * 4096 + trk) * 256 + j] = f2bf(e);
}

// -------------------------------------------------------------------------
// Fused LSTM-cell GEMM — EXACT R2 geometry (67.2 µs measured, conflicts 0):
// 128x128 block, BK=64, 4 waves (2x2 of 64x64), mfma_f32_16x16x32_bf16,
// global_load_lds width 16, XOR chunk swizzle, plain __launch_bounds__(256).
// NO fused tail code (R5 post-mortem: tail fusion -> 21MB/dispatch scratch
// spills in the K-loop, 4.5x regression).
// -------------------------------------------------------------------------
__global__ __launch_bounds__(256) void gemm_lstm(
    const uint16_t* __restrict__ X,   const uint16_t* __restrict__ Hin,
    const uint16_t* __restrict__ Wih, const uint16_t* __restrict__ Whh,
    const float* __restrict__ bias,   float* __restrict__ Cst,
    uint16_t* __restrict__ Hout,
    const float* __restrict__ obs1,   const float* __restrict__ obs2,
    int k0, int maskmode)
{
  __shared__ uint16_t As[128 * 64];
  __shared__ uint16_t Bs[128 * 64];
  __shared__ uint8_t  smask[128];

  const int tid  = threadIdx.x;
  const int wave = tid >> 6;
  const int lane = tid & 63;
  const int bm = blockIdx.y * 128;   // track rows
  const int bn = blockIdx.x * 128;   // permuted gate cols

  if (tid < 128) {
    bool m = true;
    if (maskmode) {
      const int row = bm + tid;
      const float a = obs1[row * 2];
      const float b = obs2[row * 2];
      m = !((a != a) || (b != b));
    }
    smask[tid] = m ? 1 : 0;
  }

  const int wrow = wave >> 1;
  const int wcol = wave & 1;
  const int quad = lane >> 4;
  const int l15  = lane & 15;
  const int m7   = l15 & 7;
  const int lr = lane >> 3;                  // row within 8-row staging chunk
  const int lj = ((lane & 7) ^ lr) * 8;      // swizzled global k-offset (elements)

  f32x4 acc[4][4];
#pragma unroll
  for (int i = 0; i < 4; i++)
#pragma unroll
    for (int j = 0; j < 4; j++) acc[i][j] = (f32x4){0.f, 0.f, 0.f, 0.f};

  auto mfma_slab = [&]() {
#pragma unroll
    for (int kk = 0; kk < 64; kk += 32) {
      short8 af[4], bf[4];
      const int jc = (((kk >> 3) + quad) ^ m7) * 8;   // swizzled read chunk
#pragma unroll
      for (int i = 0; i < 4; i++) {
        af[i] = *(const short8*)(As + (wrow * 64 + i * 16 + l15) * 64 + jc);
        bf[i] = *(const short8*)(Bs + (wcol * 64 + i * 16 + l15) * 64 + jc);
      }
#pragma unroll
      for (int i = 0; i < 4; i++)
#pragma unroll
        for (int j = 0; j < 4; j++)
          acc[i][j] = __builtin_amdgcn_mfma_f32_16x16x32_bf16(af[i], bf[j], acc[i][j], 0, 0, 0);
    }
  };

  // ---- phase A: X | Wih segment (row stride 256), skipped for tag step ----
  if (k0 == 0) {
    for (int kt = 0; kt < 256; kt += 64) {
      __syncthreads();
#pragma unroll
      for (int cc = 0; cc < 8; cc++) {
        const bool isA = cc < 4;
        const int trow = ((cc & 3) * 4 + wave) * 8;
        const int grow = (isA ? bm : bn) + trow + lr;
        const uint16_t* gsrc = (isA ? X : Wih) + (size_t)grow * 256 + (kt + lj);
        uint16_t* lbase = (isA ? As : Bs) + trow * 64;
        __builtin_amdgcn_global_load_lds((GV*)gsrc, (LV*)lbase, 16, 0, 0);
      }
      __syncthreads();
      mfma_slab();
    }
  }

  // ---- phase B: Hin | Whh segment (row stride 1024) ----
  for (int kt = 0; kt < 1024; kt += 64) {
    __syncthreads();
#pragma unroll
    for (int cc = 0; cc < 8; cc++) {
      const bool isA = cc < 4;
      const int trow = ((cc & 3) * 4 + wave) * 8;
      const int grow = (isA ? bm : bn) + trow + lr;
      const uint16_t* gsrc = (isA ? Hin : Whh) + (size_t)grow * 1024 + (kt + lj);
      uint16_t* lbase = (isA ? As : Bs) + trow * 64;
      __builtin_amdgcn_global_load_lds((GV*)gsrc, (LV*)lbase, 16, 0, 0);
    }
    __syncthreads();
    mfma_slab();
  }

  // Epilogue: N-tiles 0..3 = gates i,f,g,o of units u = ((bn>>6)+wcol)*16+l15.
  // C/D layout: col = lane&15, row = quad*4 + reg  [m89-verified]
  const int u  = ((bn >> 6) + wcol) * 16 + l15;
  const int jb = bn + wcol * 64 + l15;
  const float b_i = bias[jb];
  const float b_f = bias[jb + 16];
  const float b_g = bias[jb + 32];
  const float b_o = bias[jb + 48];

#pragma unroll
  for (int mi = 0; mi < 4; mi++) {
#pragma unroll
    for (int r = 0; r < 4; r++) {
      const int row = bm + wrow * 64 + mi * 16 + quad * 4 + r;
      const size_t idx = (size_t)row * 1024 + u;
      uint16_t hv;
      if (smask[row - bm]) {
        const float gi = acc[mi][0][r] + b_i;
        const float gf = acc[mi][1][r] + b_f;
        const float gg = acc[mi][2][r] + b_g;
        const float go = acc[mi][3][r] + b_o;
        const float cn = sigmf_(gf) * Cst[idx] + sigmf_(gi) * tanhf_(gg);
        Cst[idx] = cn;
        hv = f2bf(sigmf_(go) * tanhf_(cn));
      } else {
        hv = Hin[idx];        // state frozen; Hout is a different buffer
      }
      Hout[idx] = hv;
    }
  }
}

// -------------------------------------------------------------------------
// h2n + outputs (+ optional fused embed for the NEXT step's X):
// raw = h @ h2n_w.T + h2n_b (one wave per track). Butterfly reduce leaves the
// full sums in ALL lanes; lane0 writes outputs; all lanes embed next X.
// -------------------------------------------------------------------------
__global__ __launch_bounds__(256) void h2n_pos(
    const uint16_t* __restrict__ H, const float* __restrict__ w5, const float* __restrict__ b5,
    const float* __restrict__ obs1, const float* __restrict__ obs2,
    float* __restrict__ outrel, float* __restrict__ outpos,
    const float* __restrict__ pprev, const float* __restrict__ ew,
    const float* __restrict__ eb, uint16_t* __restrict__ Xnext, int do_embed)
{
  const int lane  = threadIdx.x & 63;
  const int track = blockIdx.x * 4 + (threadIdx.x >> 6);

  const uint16_t* hrow = H + (size_t)track * 1024 + lane * 16;
  const short8 v0 = *(const short8*)(hrow);
  const short8 v1 = *(const short8*)(hrow + 8);
  float hv[16];
#pragma unroll
  for (int j = 0; j < 8; j++) {
    hv[j]     = bf2f((uint16_t)v0[j]);
    hv[8 + j] = bf2f((uint16_t)v1[j]);
  }
  const int kb = lane * 16;
  float p[5];
#pragma unroll
  for (int o = 0; o < 5; o++) {
    const float* wr = w5 + (size_t)o * 1024 + kb;
    float s = 0.f;
#pragma unroll
    for (int j = 0; j < 16; j++) s += hv[j] * wr[j];
    p[o] = s;
  }
#pragma unroll
  for (int o = 0; o < 5; o++) {
    float v = p[o];
    v += __shfl_xor(v, 32); v += __shfl_xor(v, 16); v += __shfl_xor(v, 8);
    v += __shfl_xor(v, 4);  v += __shfl_xor(v, 2);  v += __shfl_xor(v, 1);
    p[o] = v;
  }
  // all lanes hold the full sums now
  const float o1x = obs1[track * 2];
  const float o2x = obs2[track * 2];
  const float o2y = obs2[track * 2 + 1];
  const bool msk = !((o1x != o1x) || (o2x != o2x));
  float n0 = p[0] + b5[0];
  float n1 = p[1] + b5[1];
  float n2 = 0.01f + 0.2f * sigmf_(p[2] + b5[2]);
  float n3 = 0.01f + 0.2f * sigmf_(p[3] + b5[3]);
  float n4 = 0.7f  * sigmf_(p[4] + b5[4]);
  if (!msk) {
    const float qn = __uint_as_float(0x7fc00000u);
    n0 = n1 = n2 = n3 = n4 = qn;
  }
  const float posx = o2x + n0;
  const float posy = o2y + n1;
  if (lane == 0) {
    float* rr = outrel + (size_t)track * 5;
    rr[0] = n0; rr[1] = n1; rr[2] = n2; rr[3] = n3; rr[4] = n4;
    outpos[track * 2]     = posx;
    outpos[track * 2 + 1] = posy;
  }
  if (do_embed) {
    const float vx = (posx - pprev[track * 2])     * 4.0f;
    const float vy = (posy - pprev[track * 2 + 1]) * 4.0f;
    uint16_t* xr = Xnext + (size_t)track * 256;
#pragma unroll
    for (int ii = 0; ii < 4; ii++) {
      const int j = ii * 64 + lane;
      float e = 0.f;
      if (j < 254) e = fmaxf(vx * ew[j * 2] + vy * ew[j * 2 + 1] + eb[j], 0.f);
      xr[j] = f2bf(e);   // NaN inputs -> fmax gives 0; row is masked anyway
    }
  }
}

// -------------------------------------------------------------------------
extern "C" void kernel_launch(void* const* d_in, const int* in_sizes, int n_in,
                              void* d_out, int out_size, void* d_ws, size_t ws_size,
                              hipStream_t stream)
{
  const float* observed = (const float*)d_in[0];
  const float* emb_w    = (const float*)d_in[1];
  const float* emb_b    = (const float*)d_in[2];
  const float* enc_wih  = (const float*)d_in[3];
  const float* enc_whh  = (const float*)d_in[4];
  const float* enc_b    = (const float*)d_in[5];
  const float* dec_wih  = (const float*)d_in[6];
  const float* dec_whh  = (const float*)d_in[7];
  const float* dec_b    = (const float*)d_in[8];
  const float* h2n_w    = (const float*)d_in[9];
  const float* h2n_b    = (const float*)d_in[10];
  // d_in[11] = n_predict (==12, fixed by setup)

  char* ws = (char*)d_ws;
  size_t off = 0;
  auto alloc = [&](size_t bytes) -> void* {
    size_t cur = (off + 255) & ~(size_t)255;
    off = cur + bytes;
    return (void*)(ws + cur);
  };
  uint16_t* WihpE = (uint16_t*)alloc((size_t)4096 * 256 * 2);
  uint16_t* WhhpE = (uint16_t*)alloc((size_t)4096 * 1024 * 2);
  uint16_t* WihpD = (uint16_t*)alloc((size_t)4096 * 256 * 2);
  uint16_t* WhhpD = (uint16_t*)alloc((size_t)4096 * 1024 * 2);
  float*    biasE = (float*)alloc(4096 * 4);
  float*    biasD = (float*)alloc(4096 * 4);
  float*    biasDT= (float*)alloc(4096 * 4);
  float*    h0    = (float*)alloc(1024 * 4);
  float*    c0    = (float*)alloc(1024 * 4);
  uint16_t* HA    = (uint16_t*)alloc((size_t)4096 * 1024 * 2);
  uint16_t* HB    = (uint16_t*)alloc((size_t)4096 * 1024 * 2);
  float*    Cst   = (float*)alloc((size_t)4096 * 1024 * 4);
  uint16_t* Xb    = (uint16_t*)alloc((size_t)4096 * 256 * 2);
  // optional batched encoder X (16 MB) — only if workspace allows
  const size_t xall_bytes = (size_t)8 * 4096 * 256 * 2;
  const bool use_xall = (off + 256 + xall_bytes) <= ws_size;
  uint16_t* Xall = use_xall ? (uint16_t*)alloc(xall_bytes) : nullptr;

  float* outrel = (float*)d_out;                     // (19, 4096, 5)
  float* outpos = outrel + (size_t)NOUT * 4096 * 5;  // (19, 4096, 2)

  prep_weights<<<4096, 256, 0, stream>>>(enc_wih, enc_whh, enc_b, dec_wih, dec_whh, dec_b,
                                         WihpE, WhhpE, WihpD, WhhpD, biasE, biasD, biasDT);
  init_h0<<<4, 256, 0, stream>>>(enc_wih, enc_b, h0, c0);
  fill_state<<<16384, 256, 0, stream>>>(h0, c0, HA, Cst);
  if (use_xall) {
    embed8<<<dim3(4096, 8), 256, 0, stream>>>(observed, emb_w, emb_b, Xall);
  }

  uint16_t* Hin = HA;
  uint16_t* Hout = HB;
  const dim3 ggrid(32, 32);

  // ---- encoder: 8 steps over observed pairs ----
  for (int t = 0; t < 8; t++) {
    const float* o1 = observed + (size_t)t * 4096 * 2;
    const float* o2 = observed + (size_t)(t + 1) * 4096 * 2;
    uint16_t* Xt = Xb;
    if (use_xall) {
      Xt = Xall + (size_t)t * 4096 * 256;
    } else {
      embed_k<<<4096, 256, 0, stream>>>(o1, o2, emb_w, emb_b, Xb);
    }
    gemm_lstm<<<ggrid, 256, 0, stream>>>(Xt, Hin, WihpE, WhhpE, biasE, Cst, Hout, o1, o2, 0, 1);
    const int de = (t == 7) ? 1 : 0;   // t==7 also embeds X for first decoder step
    h2n_pos<<<1024, 256, 0, stream>>>(Hout, h2n_w, h2n_b, o1, o2,
                                      outrel + (size_t)t * 4096 * 5,
                                      outpos + (size_t)t * 4096 * 2,
                                      outpos + (size_t)6 * 4096 * 2, emb_w, emb_b, Xb, de);
    uint16_t* tmp = Hin; Hin = Hout; Hout = tmp;
  }

  // ---- decoder tag cell (x one-hot folded into biasDT; k0=256 skips X) ----
  gemm_lstm<<<ggrid, 256, 0, stream>>>(nullptr, Hin, WihpD, WhhpD, biasDT, Cst, Hout,
                                       nullptr, nullptr, 256, 0);
  { uint16_t* tmp = Hin; Hin = Hout; Hout = tmp; }

  // ---- decoder: 11 steps; X comes from the previous step's fused h2n ----
  for (int s = 0; s < 11; s++) {
    const float* p1 = outpos + (size_t)(6 + s) * 4096 * 2;
    const float* p2 = outpos + (size_t)(7 + s) * 4096 * 2;
    gemm_lstm<<<ggrid, 256, 0, stream>>>(Xb, Hin, WihpD, WhhpD, biasD, Cst, Hout, p1, p2, 0, 1);
    const int de = (s < 10) ? 1 : 0;   // last step needs no next X
    h2n_pos<<<1024, 256, 0, stream>>>(Hout, h2n_w, h2n_b, p1, p2,
                                      outrel + (size_t)(8 + s) * 4096 * 5,
                                      outpos + (size_t)(8 + s) * 4096 * 2,
                                      p2, emb_w, emb_b, Xb, de);
    uint16_t* tmp = Hin; Hin = Hout; Hout = tmp;
  }
}